// Round 7
// baseline (216.871 us; speedup 1.0000x reference)
//
#include <hip/hip_runtime.h>

// SparseConv1D on MI355X, round 14.
// out[b,o,l] = sum_{t,i} W[o,i,t] * x[b,i,l+tap_t] = 32 shifted GEMMs (MFMA 16x16x32 bf16).
// R14 model fix (R13 depth-4 W = exact null): 4.6 cyc/MFMA is per-CU WALL, not per-SIMD.
// Per-tap wall: MFMA 590 > W-L1 512 > B-LDS 384 cyc; measured 781 => tap loop ~75% MFMA-
// bound, overlap already good — why R8/R12/R13 were flat. Remaining fat = STAGE (~13us vs
// ~4 floor; 64MB f32 with 4x halo overfetch, L2/L3 poisoned each iter) and epilogue (~3us,
// half the waves idle). R14:
//  - Core-first two-phase stage: phase-1 = rows [-64,320) only (96KB/block); run the 13
//    central taps (|TAP|<=8, order {10..22}) while staging the 640 halo rows (phase-2,
//    after each tap's MFMAs); halo rows = neighbors' phase-1 cores -> L2 hits. ONE extra
//    barrier at j==13 before the far taps {0..9,23..31}.
//  - Tap order permuted via constexpr ORD[] (all W/B addressing static).
//  - Epilogue split: ch=0 writes m01 (reduces ch1's m01 via LDS), ch=1 writes m23.
//  - Tap engine (W global->reg dbuf, B LDS dbuf, XOR-involution swizzle) unchanged.

#define B_    16
#define CIN   64
#define COUT  64
#define LEN   4096
#define NTAP  32

typedef float f32x4 __attribute__((ext_vector_type(4)));
typedef short bf16x8_s __attribute__((ext_vector_type(8)));
typedef __bf16 bf16x8_b __attribute__((ext_vector_type(8)));

template <typename V>
static __device__ inline auto mfma_16x16x32_bf16(V a, V b, f32x4 c, int)
    -> decltype(__builtin_amdgcn_mfma_f32_16x16x32_bf16(a, b, c, 0, 0, 0)) {
  return __builtin_amdgcn_mfma_f32_16x16x32_bf16(a, b, c, 0, 0, 0);
}
template <typename V>
static __device__ inline f32x4 mfma_16x16x32_bf16(V a, V b, f32x4 c, long) {
  return __builtin_amdgcn_mfma_f32_16x16x32_bf16(
      __builtin_bit_cast(bf16x8_b, a), __builtin_bit_cast(bf16x8_b, b), c, 0, 0, 0);
}

static __device__ inline unsigned short f32_to_bf16_rne(float f) {
  unsigned int u = __builtin_bit_cast(unsigned int, f);
  u += 0x7fffu + ((u >> 16) & 1u);
  return (unsigned short)(u >> 16);
}

// ---- prep_w: w[o][i][t] f32 -> Wf[t][c][m][lane][8] bf16 (frag-major, 8KB/tap) ----
__global__ __launch_bounds__(256) void prep_w(const float* __restrict__ w,
                                              unsigned short* __restrict__ wf) {
  const int base = blockIdx.x * 1024;          // grid 128 -> 131072 elems
#pragma unroll
  for (int it = 0; it < 4; ++it) {
    const int e = base + it * 256 + threadIdx.x;
    const int j = e & 7;
    const int lane = (e >> 3) & 63;
    const int m = (e >> 9) & 3;
    const int c = (e >> 11) & 1;
    const int t = e >> 12;
    const int o = m * 16 + (lane & 15);
    const int i = c * 32 + (lane >> 4) * 8 + j;
    wf[e] = f32_to_bf16_rne(w[(size_t)(o * CIN + i) * NTAP + t]);
  }
}

// ------- main: core-first 2-phase stage, permuted taps, split epilogue ----------------
__global__ __launch_bounds__(512, 2) void sconv_main(const float* __restrict__ x,
                                                     const unsigned short* __restrict__ wf,
                                                     float* __restrict__ out) {
  constexpr int TAP[NTAP] = {-512, -256, -128, -96, -64, -48, -32, -24, -16, -12, -8,
                             -6,   -4,   -3,   -2,  -1,  0,   1,   2,   3,   4,  6,
                             8,    12,   16,   24,  32,  48,  64,  96,  128, 256};
  // central taps (windows within phase-1 rows [-64,320)) first, then far taps
  constexpr int ORD[NTAP] = {10, 11, 12, 13, 14, 15, 16, 17, 18, 19, 20, 21, 22,
                             0,  1,  2,  3,  4,  5,  6,  7,  8,  9,
                             23, 24, 25, 26, 27, 28, 29, 30, 31};
  // phase-2 stage chunks (64 rows each), issued during taps j=0..9
  constexpr int P2[10] = {-128, -192, -256, -320, -384, -448, -512, 320, 384, 448};
  __shared__ alignas(16) char smem[131072];   // ring: 1024 rows x 128B

  const int id = blockIdx.x;                  // 256 blocks = 16 b x 16 l-tiles
  const int b = (id & 7) * 2 + (id >> 7);     // XCD k <- batches {2k,2k+1}
  const int l0 = ((id >> 3) & 15) * 256;      // 16 l-tiles of 256; same-XCD = same b pair
  const int lb = l0 + 512;                    // ring-phase base (mult of 256)
  const int tid = threadIdx.x;
  const int wv = tid >> 6, lane = tid & 63;
  const int q = lane >> 4, r = lane & 15;
  const int lh = wv >> 1, ch = wv & 1;        // wave: l-quarter (64 l), i-half (32 i)

  const char* wbase = (const char*)wf;
  const float* xb = x + (size_t)b * CIN * LEN;

  // stage one [64 l][64 i] chunk at window rows [lc, lc+64): f32 -> bf16 -> swizzled ring.
  // lane map: h=lane&7 -> i0=16*(wv&3)+2h ; row0 = lc + (wv>>2)*32 + (lane>>3)*4.
  // write swizzle = readB's involution: chunk' = (i0>>3) ^ (slot&7).
  auto stage_iter = [&](int lc) {
    const int h = lane & 7;
    const int i0 = 16 * (wv & 3) + 2 * h;
    const int row0 = lc + ((wv >> 2) << 5) + ((lane >> 3) << 2);
    const int gl = l0 + row0;                  // global l of the 4-quad (mult of 4)
    f32x4 va = {0.f, 0.f, 0.f, 0.f}, vb = {0.f, 0.f, 0.f, 0.f};
    if ((unsigned)gl < (unsigned)LEN) {
      va = *(const f32x4*)&xb[(size_t)i0 * LEN + gl];
      vb = *(const f32x4*)&xb[(size_t)(i0 + 1) * LEN + gl];
    }
#pragma unroll
    for (int j = 0; j < 4; ++j) {
      const unsigned u = (unsigned)f32_to_bf16_rne(va[j]) |
                         ((unsigned)f32_to_bf16_rne(vb[j]) << 16);
      const int slot = (lb + row0 + j) & 1023;
      const int cs = (i0 >> 3) ^ (slot & 7);
      *(unsigned*)(smem + slot * 128 + (cs << 4) + (i0 & 7) * 2) = u;
    }
  };

  bf16x8_s Wreg[2][4], Breg[2][4];
  f32x4 acc[4][4] = {};

  auto loadW = [&](int tt, int p) {            // global, frag-major, coalesced, L2-hit
    const char* src = wbase + tt * 8192 + ch * 4096 + lane * 16;
#pragma unroll
    for (int m = 0; m < 4; ++m)
      Wreg[p][m] = *(const bf16x8_s*)(src + m * 1024);
  };
  // slot&7 == (TAP+r)&7 (lb, lh*64, 16n all 0 mod 8) -> same involution as the write side
  auto readB = [&](int tt, int p) {
    const int e = (TAP[tt] + r) & 7;
#pragma unroll
    for (int n = 0; n < 4; ++n) {
      const int slot = (lb + TAP[tt] + lh * 64 + 16 * n + r) & 1023;
      Breg[p][n] = *(const bf16x8_s*)(smem + slot * 128 + (((ch * 4 + q) ^ e) << 4));
    }
  };

  // ---- phase-1 stage: CORE first (rows [0,256)), then [256,320) and [-64,0) ----
  loadW(ORD[0], 0);
  stage_iter(0);
  stage_iter(64);
  stage_iter(128);
  stage_iter(192);
  stage_iter(256);
  stage_iter(-64);
  __syncthreads();                             // phase-1 rows resident
  readB(ORD[0], 0);

  // ---- tap loop, permuted order; phase-2 halo staged under taps 0..9 ----
#pragma unroll
  for (int j = 0; j < NTAP; ++j) {
    const int p = j & 1;
    if (j == 13) {
      __syncthreads();                         // phase-2 rows resident (writes issued j<=9)
      readB(ORD[13], p);                       // no prefetch lead across the barrier
    }
    if (j + 1 < NTAP) {
      loadW(ORD[j + 1], p ^ 1);                // vmcnt-counted, 2-deep dbuf
      if (j != 12) readB(ORD[j + 1], p ^ 1);   // lgkmcnt-counted (skip across barrier)
    }
    __builtin_amdgcn_sched_barrier(0);         // pin prefetch issue above this tap's MFMAs
#pragma unroll
    for (int m = 0; m < 4; ++m)
#pragma unroll
      for (int n = 0; n < 4; ++n)
        acc[m][n] = mfma_16x16x32_bf16(Wreg[p][m], Breg[p][n], acc[m][n], 0);
    __builtin_amdgcn_sched_barrier(0);         // keep stage below the MFMAs
    if (j < 10) stage_iter(P2[j]);             // halo chunk: L2-hit, hidden under pipe drain
  }

  // ---- split epilogue: ch0 -> out m{0,1} (reduce ch1's via LDS); ch1 -> out m{2,3} ----
  __syncthreads();
  {
    const int mstore = (ch == 0) ? 2 : 0;      // half this ch does NOT write out
    const int sstore = (ch == 0) ? 16384 : 0;  // ch0 parks m23 at side1, ch1 parks m01 at side0
#pragma unroll
    for (int mm = 0; mm < 2; ++mm)
#pragma unroll
      for (int n = 0; n < 4; ++n)
        *(f32x4*)(smem + lh * 32768 + sstore + ((mm * 4 + n) * 64 + lane) * 16) =
            acc[mstore + mm][n];
  }
  __syncthreads();
  {
    const int mout = (ch == 0) ? 0 : 2;        // half this ch writes out
    const int sread = (ch == 0) ? 0 : 16384;   // where the OTHER ch parked that half
#pragma unroll
    for (int mm = 0; mm < 2; ++mm)
#pragma unroll
      for (int n = 0; n < 4; ++n) {
        const f32x4 other =
            *(const f32x4*)(smem + lh * 32768 + sread + ((mm * 4 + n) * 64 + lane) * 16);
        const f32x4 v = acc[mout + mm][n] + other;
        // C/D layout (verified): col(l) = lane&15, row(o) = (lane>>4)*4 + reg
#pragma unroll
        for (int d = 0; d < 4; ++d) {
          const int o = 16 * (mout + mm) + 4 * q + d;
          const int l = l0 + lh * 64 + 16 * n + r;
          out[((size_t)b * COUT + o) * LEN + l] = v[d];
        }
      }
  }
}

extern "C" void kernel_launch(void* const* d_in, const int* in_sizes, int n_in,
                              void* d_out, int out_size, void* d_ws, size_t ws_size,
                              hipStream_t stream) {
  const float* x = (const float*)d_in[0];        // [16][64][4096]
  const float* w = (const float*)d_in[1];        // [64][64][32]
  float* out = (float*)d_out;                    // [16][64][4096]

  unsigned short* wfp = (unsigned short*)d_ws;   // 256 KB frag-major W

  prep_w<<<dim3(128), 256, 0, stream>>>(w, wfp);
  sconv_main<<<dim3(256), 512, 0, stream>>>(x, wfp, out);
}

// Round 8
// 89.324 us; speedup vs baseline: 2.4279x; 2.4279x over previous
//
#include <hip/hip_runtime.h>

// SparseConv1D on MI355X, round 15.
// out[b,o,l] = sum_{t,i} W[o,i,t] * x[b,i,l+tap_t] = 32 shifted GEMMs (MFMA 16x16x32 bf16).
// R15 = R14 with the scratch-spill fixed (rule #20). R14's 157us regression signature:
// WRITE_SIZE 718MB (42x output), MfmaUtil 4%, VGPR=100 => acc[4][4] demoted to LOCAL MEMORY
// because the split epilogue indexed it as acc[mstore+mm] with runtime mstore=(ch==0)?2:0.
// Every MFMA accumulation round-tripped scratch (256B/thr x 131k thr ~= the 700MB seen).
// Fix: epilogue branches on ch with ALL acc indices compile-time literals.
// Unchanged from R14 (untested ideas, now actually benched):
//  - Core-first phase-1 stage: rows [-64,320) (6 chunks); 13 central taps (ORD {10..22})
//    run while 10 halo chunks stage under taps j=0..9; ONE extra barrier at j==13.
//  - Epilogue write-split: ch0 writes o[0,32), ch1 writes o[32,64) (was: ch1 idle).
//  - Tap engine (W global->reg dbuf, B LDS dbuf, XOR-involution swizzle) = R10/R13 proven.

#define B_    16
#define CIN   64
#define COUT  64
#define LEN   4096
#define NTAP  32

typedef float f32x4 __attribute__((ext_vector_type(4)));
typedef short bf16x8_s __attribute__((ext_vector_type(8)));
typedef __bf16 bf16x8_b __attribute__((ext_vector_type(8)));

template <typename V>
static __device__ inline auto mfma_16x16x32_bf16(V a, V b, f32x4 c, int)
    -> decltype(__builtin_amdgcn_mfma_f32_16x16x32_bf16(a, b, c, 0, 0, 0)) {
  return __builtin_amdgcn_mfma_f32_16x16x32_bf16(a, b, c, 0, 0, 0);
}
template <typename V>
static __device__ inline f32x4 mfma_16x16x32_bf16(V a, V b, f32x4 c, long) {
  return __builtin_amdgcn_mfma_f32_16x16x32_bf16(
      __builtin_bit_cast(bf16x8_b, a), __builtin_bit_cast(bf16x8_b, b), c, 0, 0, 0);
}

static __device__ inline unsigned short f32_to_bf16_rne(float f) {
  unsigned int u = __builtin_bit_cast(unsigned int, f);
  u += 0x7fffu + ((u >> 16) & 1u);
  return (unsigned short)(u >> 16);
}

// ---- prep_w: w[o][i][t] f32 -> Wf[t][c][m][lane][8] bf16 (frag-major, 8KB/tap) ----
__global__ __launch_bounds__(256) void prep_w(const float* __restrict__ w,
                                              unsigned short* __restrict__ wf) {
  const int base = blockIdx.x * 1024;          // grid 128 -> 131072 elems
#pragma unroll
  for (int it = 0; it < 4; ++it) {
    const int e = base + it * 256 + threadIdx.x;
    const int j = e & 7;
    const int lane = (e >> 3) & 63;
    const int m = (e >> 9) & 3;
    const int c = (e >> 11) & 1;
    const int t = e >> 12;
    const int o = m * 16 + (lane & 15);
    const int i = c * 32 + (lane >> 4) * 8 + j;
    wf[e] = f32_to_bf16_rne(w[(size_t)(o * CIN + i) * NTAP + t]);
  }
}

// ------- main: core-first 2-phase stage, permuted taps, STATIC split epilogue ----------
__global__ __launch_bounds__(512, 2) void sconv_main(const float* __restrict__ x,
                                                     const unsigned short* __restrict__ wf,
                                                     float* __restrict__ out) {
  constexpr int TAP[NTAP] = {-512, -256, -128, -96, -64, -48, -32, -24, -16, -12, -8,
                             -6,   -4,   -3,   -2,  -1,  0,   1,   2,   3,   4,  6,
                             8,    12,   16,   24,  32,  48,  64,  96,  128, 256};
  // central taps (windows within phase-1 rows [-64,320)) first, then far taps
  constexpr int ORD[NTAP] = {10, 11, 12, 13, 14, 15, 16, 17, 18, 19, 20, 21, 22,
                             0,  1,  2,  3,  4,  5,  6,  7,  8,  9,
                             23, 24, 25, 26, 27, 28, 29, 30, 31};
  // phase-2 stage chunks (64 rows each), issued during taps j=0..9
  constexpr int P2[10] = {-128, -192, -256, -320, -384, -448, -512, 320, 384, 448};
  __shared__ alignas(16) char smem[131072];   // ring: 1024 rows x 128B

  const int id = blockIdx.x;                  // 256 blocks = 16 b x 16 l-tiles
  const int b = (id & 7) * 2 + (id >> 7);     // XCD k <- batches {2k,2k+1}
  const int l0 = ((id >> 3) & 15) * 256;      // 16 l-tiles of 256
  const int lb = l0 + 512;                    // ring-phase base (mult of 256)
  const int tid = threadIdx.x;
  const int wv = tid >> 6, lane = tid & 63;
  const int q = lane >> 4, r = lane & 15;
  const int lh = wv >> 1, ch = wv & 1;        // wave: l-quarter (64 l), i-half (32 i)

  const char* wbase = (const char*)wf;
  const float* xb = x + (size_t)b * CIN * LEN;

  // stage one [64 l][64 i] chunk at window rows [lc, lc+64): f32 -> bf16 -> swizzled ring.
  // lane map: h=lane&7 -> i0=16*(wv&3)+2h ; row0 = lc + (wv>>2)*32 + (lane>>3)*4.
  // write swizzle = readB's involution: chunk' = (i0>>3) ^ (slot&7).
  auto stage_iter = [&](int lc) {
    const int h = lane & 7;
    const int i0 = 16 * (wv & 3) + 2 * h;
    const int row0 = lc + ((wv >> 2) << 5) + ((lane >> 3) << 2);
    const int gl = l0 + row0;                  // global l of the 4-quad (mult of 4)
    f32x4 va = {0.f, 0.f, 0.f, 0.f}, vb = {0.f, 0.f, 0.f, 0.f};
    if ((unsigned)gl < (unsigned)LEN) {
      va = *(const f32x4*)&xb[(size_t)i0 * LEN + gl];
      vb = *(const f32x4*)&xb[(size_t)(i0 + 1) * LEN + gl];
    }
#pragma unroll
    for (int j = 0; j < 4; ++j) {
      const unsigned u = (unsigned)f32_to_bf16_rne(va[j]) |
                         ((unsigned)f32_to_bf16_rne(vb[j]) << 16);
      const int slot = (lb + row0 + j) & 1023;
      const int cs = (i0 >> 3) ^ (slot & 7);
      *(unsigned*)(smem + slot * 128 + (cs << 4) + (i0 & 7) * 2) = u;
    }
  };

  bf16x8_s Wreg[2][4], Breg[2][4];
  f32x4 acc[4][4] = {};

  auto loadW = [&](int tt, int p) {            // global, frag-major, coalesced, L2-hit
    const char* src = wbase + tt * 8192 + ch * 4096 + lane * 16;
#pragma unroll
    for (int m = 0; m < 4; ++m)
      Wreg[p][m] = *(const bf16x8_s*)(src + m * 1024);
  };
  // slot&7 == (TAP+r)&7 (lb, lh*64, 16n all 0 mod 8) -> same involution as the write side
  auto readB = [&](int tt, int p) {
    const int e = (TAP[tt] + r) & 7;
#pragma unroll
    for (int n = 0; n < 4; ++n) {
      const int slot = (lb + TAP[tt] + lh * 64 + 16 * n + r) & 1023;
      Breg[p][n] = *(const bf16x8_s*)(smem + slot * 128 + (((ch * 4 + q) ^ e) << 4));
    }
  };

  // ---- phase-1 stage: CORE first (rows [0,256)), then [256,320) and [-64,0) ----
  loadW(ORD[0], 0);
  stage_iter(0);
  stage_iter(64);
  stage_iter(128);
  stage_iter(192);
  stage_iter(256);
  stage_iter(-64);
  __syncthreads();                             // phase-1 rows resident
  readB(ORD[0], 0);

  // ---- tap loop, permuted order; phase-2 halo staged under taps 0..9 ----
#pragma unroll
  for (int j = 0; j < NTAP; ++j) {
    const int p = j & 1;
    if (j == 13) {
      __syncthreads();                         // phase-2 rows resident (writes issued j<=9)
      readB(ORD[13], p);                       // no prefetch lead across the barrier
    }
    if (j + 1 < NTAP) {
      loadW(ORD[j + 1], p ^ 1);                // vmcnt-counted, 2-deep dbuf
      if (j != 12) readB(ORD[j + 1], p ^ 1);   // lgkmcnt-counted (skip across barrier)
    }
    __builtin_amdgcn_sched_barrier(0);         // pin prefetch issue above this tap's MFMAs
#pragma unroll
    for (int m = 0; m < 4; ++m)
#pragma unroll
      for (int n = 0; n < 4; ++n)
        acc[m][n] = mfma_16x16x32_bf16(Wreg[p][m], Breg[p][n], acc[m][n], 0);
    __builtin_amdgcn_sched_barrier(0);         // keep stage below the MFMAs
    if (j < 10) stage_iter(P2[j]);             // halo chunk: L2-hit, hidden under pipe drain
  }

  // ---- split epilogue, ALL acc indices static (rule #20 fix) ----
  // ch0 parks m2,m3 at side 16384; ch1 parks m0,m1 at side 0. Then ch0 reduces+writes
  // m0,m1 (o in [0,32)); ch1 reduces+writes m2,m3 (o in [32,64)).
  __syncthreads();
  if (ch == 0) {
#pragma unroll
    for (int n = 0; n < 4; ++n) {
      *(f32x4*)(smem + lh * 32768 + 16384 + ((0 * 4 + n) * 64 + lane) * 16) = acc[2][n];
      *(f32x4*)(smem + lh * 32768 + 16384 + ((1 * 4 + n) * 64 + lane) * 16) = acc[3][n];
    }
  } else {
#pragma unroll
    for (int n = 0; n < 4; ++n) {
      *(f32x4*)(smem + lh * 32768 + ((0 * 4 + n) * 64 + lane) * 16) = acc[0][n];
      *(f32x4*)(smem + lh * 32768 + ((1 * 4 + n) * 64 + lane) * 16) = acc[1][n];
    }
  }
  __syncthreads();
  // C/D layout (verified): col(l) = lane&15, row(o) = (lane>>4)*4 + reg
  if (ch == 0) {
#pragma unroll
    for (int n = 0; n < 4; ++n) {
      const f32x4 o0 = *(const f32x4*)(smem + lh * 32768 + ((0 * 4 + n) * 64 + lane) * 16);
      const f32x4 o1 = *(const f32x4*)(smem + lh * 32768 + ((1 * 4 + n) * 64 + lane) * 16);
      const f32x4 v0 = acc[0][n] + o0;
      const f32x4 v1 = acc[1][n] + o1;
      const int l = l0 + lh * 64 + 16 * n + r;
#pragma unroll
      for (int d = 0; d < 4; ++d) {
        out[((size_t)b * COUT + (0 + 4 * q + d)) * LEN + l] = v0[d];
        out[((size_t)b * COUT + (16 + 4 * q + d)) * LEN + l] = v1[d];
      }
    }
  } else {
#pragma unroll
    for (int n = 0; n < 4; ++n) {
      const f32x4 o2 = *(const f32x4*)(smem + lh * 32768 + 16384 + ((0 * 4 + n) * 64 + lane) * 16);
      const f32x4 o3 = *(const f32x4*)(smem + lh * 32768 + 16384 + ((1 * 4 + n) * 64 + lane) * 16);
      const f32x4 v2 = acc[2][n] + o2;
      const f32x4 v3 = acc[3][n] + o3;
      const int l = l0 + lh * 64 + 16 * n + r;
#pragma unroll
      for (int d = 0; d < 4; ++d) {
        out[((size_t)b * COUT + (32 + 4 * q + d)) * LEN + l] = v2[d];
        out[((size_t)b * COUT + (48 + 4 * q + d)) * LEN + l] = v3[d];
      }
    }
  }
}

extern "C" void kernel_launch(void* const* d_in, const int* in_sizes, int n_in,
                              void* d_out, int out_size, void* d_ws, size_t ws_size,
                              hipStream_t stream) {
  const float* x = (const float*)d_in[0];        // [16][64][4096]
  const float* w = (const float*)d_in[1];        // [64][64][32]
  float* out = (float*)d_out;                    // [16][64][4096]

  unsigned short* wfp = (unsigned short*)d_ws;   // 256 KB frag-major W

  prep_w<<<dim3(128), 256, 0, stream>>>(w, wfp);
  sconv_main<<<dim3(256), 512, 0, stream>>>(x, wfp, out);
}